// Round 2
// baseline (1701.381 us; speedup 1.0000x reference)
//
#include <hip/hip_runtime.h>
#include <hip/hip_bf16.h>
#include <stdint.h>

#define SEQ    2048
#define HIDDEN 4096
#define INTER  11008

typedef short bf16x8 __attribute__((ext_vector_type(8)));
typedef float f32x4  __attribute__((ext_vector_type(4)));

__device__ __forceinline__ unsigned short f2bf(float f) {
    union { __hip_bfloat16 h; unsigned short u; } v;
    v.h = __float2bfloat16(f);
    return v.u;
}

__device__ __forceinline__ void gload_lds16(const void* g, void* lds) {
    __builtin_amdgcn_global_load_lds(
        (const __attribute__((address_space(1))) uint32_t*)g,
        (__attribute__((address_space(3))) uint32_t*)lds,
        16, 0, 0);
}

// ---------------------------------------------------------------------------
// Kernel 1: x fp32 -> bf16
// ---------------------------------------------------------------------------
__global__ __launch_bounds__(256) void k_cvt_x(const float* __restrict__ x,
                                               unsigned short* __restrict__ xb) {
    int i = (blockIdx.x * 256 + threadIdx.x) * 4;
    float4 v = *(const float4*)(x + i);
    ushort4 o;
    o.x = f2bf(v.x); o.y = f2bf(v.y); o.z = f2bf(v.z); o.w = f2bf(v.w);
    *(ushort4*)(xb + i) = o;
}

// ---------------------------------------------------------------------------
// Kernel 2: fused gate+up GEMM + SwiGLU -> h (bf16)
// 512 thr (8 waves: 2M x 4N). Tile: 128(M) x 128(N), BK=64.
// Wave tile: 64(M) x 32(N) for BOTH gate and up.
// Grid: 1376 blocks, L3-chunked order (2 chunks of 43 N-tiles x 16 M-tiles).
// ---------------------------------------------------------------------------
__global__ __launch_bounds__(512) void k_gate_up(
    const unsigned short* __restrict__ xb,   // [SEQ][HIDDEN] bf16
    const int* __restrict__ gqw, const int* __restrict__ gqz,
    const float* __restrict__ gsc, const float* __restrict__ gbias,
    const int* __restrict__ uqw, const int* __restrict__ uqz,
    const float* __restrict__ usc, const float* __restrict__ ubias,
    unsigned short* __restrict__ h)          // [SEQ][INTER] bf16
{
    __shared__ __align__(16) unsigned short At[128 * 64]; // 16 KB, swizzled
    __shared__ __align__(16) unsigned short Bg[128 * 64]; // 16 KB, swizzled
    __shared__ __align__(16) unsigned short Bu[128 * 64]; // 16 KB, swizzled

    // ---- L3-chunked bid decode: chunk of 43 N-tiles covers all 16 M-tiles
    const int bid = blockIdx.x;              // 0..1375
    const int c   = bid / (43 * 16);
    const int rem = bid % (43 * 16);
    const int mt  = rem / 43;
    const int nt  = c * 43 + rem % 43;
    const int m0  = mt * 128;                // SEQ offset
    const int n0  = nt * 128;                // INTER offset

    const int t    = threadIdx.x;
    const int lane = t & 63;
    const int wave = t >> 6;
    const int wm = (wave >> 2) * 64;         // wave M offset in tile
    const int wn = (wave & 3) * 32;          // wave N offset in tile

    f32x4 accG[4][2], accU[4][2];
#pragma unroll
    for (int mi = 0; mi < 4; ++mi)
#pragma unroll
        for (int ni = 0; ni < 2; ++ni) {
            accG[mi][ni] = (f32x4){0.f, 0.f, 0.f, 0.f};
            accU[mi][ni] = (f32x4){0.f, 0.f, 0.f, 0.f};
        }

    for (int kt = 0; kt < HIDDEN / 64; ++kt) {
        const int k0  = kt * 64;
        const int grp = k0 >> 7;   // constant within tile (64 | 128)

        // ---- stage A (x tile 128x64) via global_load_lds, pre-swizzled src
#pragma unroll
        for (int cc = 0; cc < 2; ++cc) {
            int idx  = t + 512 * cc;         // 16B chunk index, 0..1023
            int row  = idx >> 3;             // 0..127
            int colb = (idx & 7) * 16;       // byte col 0..112
            int scol = colb ^ ((row & 7) << 4);
            const char* g = (const char*)(xb + (size_t)(m0 + row) * HIDDEN + k0) + scol;
            gload_lds16(g, (char*)At + idx * 16);
        }

        // ---- stage B gate & up (128 rows x 64 codes): dequant + swizzled write
#pragma unroll
        for (int cc = 0; cc < 4; ++cc) {
            int row  = (t >> 4) + 32 * cc;   // 0..127 (output col within tile)
            int col4 = (t & 15) * 4;         // code col 0..60
            int gi   = n0 + row;
            int lbyte = row * 128 + ((col4 * 2) ^ ((row & 7) << 4));
            {
                int4  q = *(const int4*)(gqw + (size_t)gi * HIDDEN + k0 + col4);
                int   z = gqz[gi * (HIDDEN / 128) + grp];
                float s = gsc[gi * (HIDDEN / 128) + grp];
                float zs = -(float)z * s;
                ushort4 w;
                w.x = f2bf(fmaf((float)q.x, s, zs));
                w.y = f2bf(fmaf((float)q.y, s, zs));
                w.z = f2bf(fmaf((float)q.z, s, zs));
                w.w = f2bf(fmaf((float)q.w, s, zs));
                *(ushort4*)((char*)Bg + lbyte) = w;
            }
            {
                int4  q = *(const int4*)(uqw + (size_t)gi * HIDDEN + k0 + col4);
                int   z = uqz[gi * (HIDDEN / 128) + grp];
                float s = usc[gi * (HIDDEN / 128) + grp];
                float zs = -(float)z * s;
                ushort4 w;
                w.x = f2bf(fmaf((float)q.x, s, zs));
                w.y = f2bf(fmaf((float)q.y, s, zs));
                w.z = f2bf(fmaf((float)q.z, s, zs));
                w.w = f2bf(fmaf((float)q.w, s, zs));
                *(ushort4*)((char*)Bu + lbyte) = w;
            }
        }

        __syncthreads();

        // ---- MFMA ----
#pragma unroll
        for (int kk = 0; kk < 2; ++kk) {
            bf16x8 af[4], bg[2], bu[2];
#pragma unroll
            for (int mi = 0; mi < 4; ++mi) {
                int row  = wm + mi * 16 + (lane & 15);
                int colb = kk * 64 + ((lane >> 4) * 16);
                af[mi] = *(const bf16x8*)((const char*)At + row * 128 +
                                          (colb ^ ((row & 7) << 4)));
            }
#pragma unroll
            for (int ni = 0; ni < 2; ++ni) {
                int row  = wn + ni * 16 + (lane & 15);
                int colb = kk * 64 + ((lane >> 4) * 16);
                int off  = row * 128 + (colb ^ ((row & 7) << 4));
                bg[ni] = *(const bf16x8*)((const char*)Bg + off);
                bu[ni] = *(const bf16x8*)((const char*)Bu + off);
            }
#pragma unroll
            for (int mi = 0; mi < 4; ++mi)
#pragma unroll
                for (int ni = 0; ni < 2; ++ni) {
                    accG[mi][ni] = __builtin_amdgcn_mfma_f32_16x16x32_bf16(
                        af[mi], bg[ni], accG[mi][ni], 0, 0, 0);
                    accU[mi][ni] = __builtin_amdgcn_mfma_f32_16x16x32_bf16(
                        af[mi], bu[ni], accU[mi][ni], 0, 0, 0);
                }
        }

        __syncthreads();
    }

    // ---- epilogue: SwiGLU, write h as bf16 ----
#pragma unroll
    for (int ni = 0; ni < 2; ++ni) {
        int col = n0 + wn + ni * 16 + (lane & 15);
        float gb = gbias[col], ub = ubias[col];
#pragma unroll
        for (int mi = 0; mi < 4; ++mi) {
#pragma unroll
            for (int j = 0; j < 4; ++j) {
                int row = m0 + wm + mi * 16 + ((lane >> 4) * 4) + j;
                float g = accG[mi][ni][j] + gb;
                float u = accU[mi][ni][j] + ub;
                float sig = 1.f / (1.f + __expf(-g));
                float hv = g * sig * u;
                h[(size_t)row * INTER + col] = f2bf(hv);
            }
        }
    }
}

// ---------------------------------------------------------------------------
// Kernel 3: down GEMM: y = h @ Wd^T + bias (fp32 out)
// 512 thr (8 waves: 2M x 4N). Tile: 128(M) x 128(N), BK=64, K=INTER.
// Grid: 512 blocks, L3-chunked (2 chunks of 16 N-tiles x 16 M-tiles).
// ---------------------------------------------------------------------------
__global__ __launch_bounds__(512) void k_down(
    const unsigned short* __restrict__ h,    // [SEQ][INTER] bf16
    const int* __restrict__ dqw, const int* __restrict__ dqz,
    const float* __restrict__ dsc, const float* __restrict__ dbias,
    float* __restrict__ y)                   // [SEQ][HIDDEN] fp32
{
    __shared__ __align__(16) unsigned short At[128 * 64]; // 16 KB
    __shared__ __align__(16) unsigned short Bd[128 * 64]; // 16 KB

    const int bid = blockIdx.x;              // 0..511
    const int c   = bid / 256;
    const int rem = bid % 256;
    const int mt  = rem / 16;
    const int nt  = c * 16 + rem % 16;
    const int m0  = mt * 128;
    const int n0  = nt * 128;

    const int t    = threadIdx.x;
    const int lane = t & 63;
    const int wave = t >> 6;
    const int wm = (wave >> 2) * 64;
    const int wn = (wave & 3) * 32;

    f32x4 acc[4][2];
#pragma unroll
    for (int mi = 0; mi < 4; ++mi)
#pragma unroll
        for (int ni = 0; ni < 2; ++ni)
            acc[mi][ni] = (f32x4){0.f, 0.f, 0.f, 0.f};

    for (int kt = 0; kt < INTER / 64; ++kt) {
        const int k0  = kt * 64;
        const int grp = k0 >> 7;

        // ---- stage A (h tile) ----
#pragma unroll
        for (int cc = 0; cc < 2; ++cc) {
            int idx  = t + 512 * cc;
            int row  = idx >> 3;
            int colb = (idx & 7) * 16;
            int scol = colb ^ ((row & 7) << 4);
            const char* g = (const char*)(h + (size_t)(m0 + row) * INTER + k0) + scol;
            gload_lds16(g, (char*)At + idx * 16);
        }

        // ---- stage B (down weights, dequant) ----
#pragma unroll
        for (int cc = 0; cc < 4; ++cc) {
            int row  = (t >> 4) + 32 * cc;
            int col4 = (t & 15) * 4;
            int gi   = n0 + row;
            int4  q = *(const int4*)(dqw + (size_t)gi * INTER + k0 + col4);
            int   z = dqz[gi * (INTER / 128) + grp];
            float s = dsc[gi * (INTER / 128) + grp];
            float zs = -(float)z * s;
            ushort4 w;
            w.x = f2bf(fmaf((float)q.x, s, zs));
            w.y = f2bf(fmaf((float)q.y, s, zs));
            w.z = f2bf(fmaf((float)q.z, s, zs));
            w.w = f2bf(fmaf((float)q.w, s, zs));
            *(ushort4*)((char*)Bd + (row * 128 + ((col4 * 2) ^ ((row & 7) << 4)))) = w;
        }

        __syncthreads();

#pragma unroll
        for (int kk = 0; kk < 2; ++kk) {
            bf16x8 af[4], bd[2];
#pragma unroll
            for (int mi = 0; mi < 4; ++mi) {
                int row  = wm + mi * 16 + (lane & 15);
                int colb = kk * 64 + ((lane >> 4) * 16);
                af[mi] = *(const bf16x8*)((const char*)At + row * 128 +
                                          (colb ^ ((row & 7) << 4)));
            }
#pragma unroll
            for (int ni = 0; ni < 2; ++ni) {
                int row  = wn + ni * 16 + (lane & 15);
                int colb = kk * 64 + ((lane >> 4) * 16);
                bd[ni] = *(const bf16x8*)((const char*)Bd + row * 128 +
                                          (colb ^ ((row & 7) << 4)));
            }
#pragma unroll
            for (int mi = 0; mi < 4; ++mi)
#pragma unroll
                for (int ni = 0; ni < 2; ++ni)
                    acc[mi][ni] = __builtin_amdgcn_mfma_f32_16x16x32_bf16(
                        af[mi], bd[ni], acc[mi][ni], 0, 0, 0);
        }

        __syncthreads();
    }

    // ---- epilogue: bias + fp32 store ----
#pragma unroll
    for (int ni = 0; ni < 2; ++ni) {
        int col = n0 + wn + ni * 16 + (lane & 15);
        float db = dbias[col];
#pragma unroll
        for (int mi = 0; mi < 4; ++mi) {
#pragma unroll
            for (int j = 0; j < 4; ++j) {
                int row = m0 + wm + mi * 16 + ((lane >> 4) * 4) + j;
                y[(size_t)row * HIDDEN + col] = acc[mi][ni][j] + db;
            }
        }
    }
}

// ---------------------------------------------------------------------------
extern "C" void kernel_launch(void* const* d_in, const int* in_sizes, int n_in,
                              void* d_out, int out_size, void* d_ws, size_t ws_size,
                              hipStream_t stream) {
    const float* x    = (const float*)d_in[0];
    const int*   gqw  = (const int*)d_in[1];
    const int*   gqz  = (const int*)d_in[2];
    const float* gsc  = (const float*)d_in[3];
    const float* gbia = (const float*)d_in[4];
    const int*   uqw  = (const int*)d_in[5];
    const int*   uqz  = (const int*)d_in[6];
    const float* usc  = (const float*)d_in[7];
    const float* ubia = (const float*)d_in[8];
    const int*   dqw  = (const int*)d_in[9];
    const int*   dqz  = (const int*)d_in[10];
    const float* dsc  = (const float*)d_in[11];
    const float* dbia = (const float*)d_in[12];
    float* y = (float*)d_out;

    unsigned short* xb = (unsigned short*)d_ws;                    // 16.8 MB
    unsigned short* hh = xb + (size_t)SEQ * HIDDEN;                // 45.1 MB

    k_cvt_x<<<(SEQ * HIDDEN) / 1024, 256, 0, stream>>>(x, xb);
    k_gate_up<<<dim3(1376), 512, 0, stream>>>(
        xb, gqw, gqz, gsc, gbia, uqw, uqz, usc, ubia, hh);
    k_down<<<dim3(512), 512, 0, stream>>>(
        hh, dqw, dqz, dsc, dbia, y);
}

// Round 3
// 1329.165 us; speedup vs baseline: 1.2800x; 1.2800x over previous
//
#include <hip/hip_runtime.h>
#include <hip/hip_bf16.h>
#include <stdint.h>

#define SEQ    2048
#define HIDDEN 4096
#define INTER  11008

typedef short bf16x8 __attribute__((ext_vector_type(8)));
typedef float f32x4  __attribute__((ext_vector_type(4)));

__device__ __forceinline__ unsigned short f2bf(float f) {
    union { __hip_bfloat16 h; unsigned short u; } v;
    v.h = __float2bfloat16(f);
    return v.u;
}

__device__ __forceinline__ void gload_lds16(const void* g, void* lds) {
    __builtin_amdgcn_global_load_lds(
        (const __attribute__((address_space(1))) uint32_t*)g,
        (__attribute__((address_space(3))) uint32_t*)lds,
        16, 0, 0);
}

// ---------------------------------------------------------------------------
// Kernel 1: x fp32 -> bf16
// ---------------------------------------------------------------------------
__global__ __launch_bounds__(256) void k_cvt_x(const float* __restrict__ x,
                                               unsigned short* __restrict__ xb) {
    int i = (blockIdx.x * 256 + threadIdx.x) * 4;
    float4 v = *(const float4*)(x + i);
    ushort4 o;
    o.x = f2bf(v.x); o.y = f2bf(v.y); o.z = f2bf(v.z); o.w = f2bf(v.w);
    *(ushort4*)(xb + i) = o;
}

// ---------------------------------------------------------------------------
// Kernel 2: fused gate+up GEMM + SwiGLU -> h (bf16)
// Block: 256 thr (4 waves). Tile: 128(M) x 64(N), BK=64.
// Wave tile: 64(M) x 32(N) for BOTH gate and up.
// Grid: 2752 blocks, 1D. bid decode: mt = bid & 15 (M-siblings ADJACENT so
// the 16 replicas of each weight byte are co-resident -> 1 HBM fetch + hits).
// ---------------------------------------------------------------------------
__global__ __launch_bounds__(256) void k_gate_up(
    const unsigned short* __restrict__ xb,   // [SEQ][HIDDEN] bf16
    const int* __restrict__ gqw, const int* __restrict__ gqz,
    const float* __restrict__ gsc, const float* __restrict__ gbias,
    const int* __restrict__ uqw, const int* __restrict__ uqz,
    const float* __restrict__ usc, const float* __restrict__ ubias,
    unsigned short* __restrict__ h)          // [SEQ][INTER] bf16
{
    __shared__ __align__(16) unsigned short At[128 * 64]; // 16 KB, swizzled
    __shared__ __align__(16) unsigned short Bg[64 * 64];  // 8 KB, swizzled
    __shared__ __align__(16) unsigned short Bu[64 * 64];  // 8 KB, swizzled

    const int bid = blockIdx.x;
    const int mt  = bid & 15;            // M-siblings adjacent
    const int nt  = bid >> 4;
    const int m0  = mt * 128;            // SEQ offset
    const int n0  = nt * 64;             // INTER offset

    const int t    = threadIdx.x;
    const int lane = t & 63;
    const int wave = t >> 6;

    const int wm = (wave >> 1) * 64;     // wave M offset in tile
    const int wn = (wave & 1) * 32;      // wave N offset in tile

    f32x4 accG[4][2], accU[4][2];
#pragma unroll
    for (int mi = 0; mi < 4; ++mi)
#pragma unroll
        for (int ni = 0; ni < 2; ++ni) {
            accG[mi][ni] = (f32x4){0.f, 0.f, 0.f, 0.f};
            accU[mi][ni] = (f32x4){0.f, 0.f, 0.f, 0.f};
        }

    for (int kt = 0; kt < HIDDEN / 64; ++kt) {
        const int k0  = kt * 64;
        const int grp = k0 >> 7;   // constant within tile (64 | 128)

        // ---- stage A (x tile) via global_load_lds, pre-swizzled source ----
#pragma unroll
        for (int c = 0; c < 4; ++c) {
            int idx  = t + 256 * c;          // 16B chunk index, 0..1023
            int row  = idx >> 3;             // 0..127
            int colb = (idx & 7) * 16;       // byte col 0..112
            int scol = colb ^ ((row & 7) << 4);
            const char* g = (const char*)(xb + (size_t)(m0 + row) * HIDDEN + k0) + scol;
            gload_lds16(g, (char*)At + idx * 16);
        }

        // ---- stage B gate & up: load codes, dequant, swizzled ds_write ----
#pragma unroll
        for (int c = 0; c < 4; ++c) {
            int row  = (t >> 4) + 16 * c;    // 0..63  (output col within tile)
            int col4 = (t & 15) * 4;         // code col 0..60
            int gi   = n0 + row;
            int lbyte = row * 128 + ((col4 * 2) ^ ((row & 7) << 4));
            {
                int4  q = *(const int4*)(gqw + (size_t)gi * HIDDEN + k0 + col4);
                int   z = gqz[gi * (HIDDEN / 128) + grp];
                float s = gsc[gi * (HIDDEN / 128) + grp];
                float zs = -(float)z * s;
                ushort4 w;
                w.x = f2bf(fmaf((float)q.x, s, zs));
                w.y = f2bf(fmaf((float)q.y, s, zs));
                w.z = f2bf(fmaf((float)q.z, s, zs));
                w.w = f2bf(fmaf((float)q.w, s, zs));
                *(ushort4*)((char*)Bg + lbyte) = w;
            }
            {
                int4  q = *(const int4*)(uqw + (size_t)gi * HIDDEN + k0 + col4);
                int   z = uqz[gi * (HIDDEN / 128) + grp];
                float s = usc[gi * (HIDDEN / 128) + grp];
                float zs = -(float)z * s;
                ushort4 w;
                w.x = f2bf(fmaf((float)q.x, s, zs));
                w.y = f2bf(fmaf((float)q.y, s, zs));
                w.z = f2bf(fmaf((float)q.z, s, zs));
                w.w = f2bf(fmaf((float)q.w, s, zs));
                *(ushort4*)((char*)Bu + lbyte) = w;
            }
        }

        __syncthreads();

        // ---- MFMA ----
#pragma unroll
        for (int kk = 0; kk < 2; ++kk) {
            bf16x8 af[4], bg[2], bu[2];
#pragma unroll
            for (int mi = 0; mi < 4; ++mi) {
                int row  = wm + mi * 16 + (lane & 15);
                int colb = kk * 64 + ((lane >> 4) * 16);
                af[mi] = *(const bf16x8*)((const char*)At + row * 128 +
                                          (colb ^ ((row & 7) << 4)));
            }
#pragma unroll
            for (int ni = 0; ni < 2; ++ni) {
                int row  = wn + ni * 16 + (lane & 15);
                int colb = kk * 64 + ((lane >> 4) * 16);
                int off  = row * 128 + (colb ^ ((row & 7) << 4));
                bg[ni] = *(const bf16x8*)((const char*)Bg + off);
                bu[ni] = *(const bf16x8*)((const char*)Bu + off);
            }
#pragma unroll
            for (int mi = 0; mi < 4; ++mi)
#pragma unroll
                for (int ni = 0; ni < 2; ++ni) {
                    accG[mi][ni] = __builtin_amdgcn_mfma_f32_16x16x32_bf16(
                        af[mi], bg[ni], accG[mi][ni], 0, 0, 0);
                    accU[mi][ni] = __builtin_amdgcn_mfma_f32_16x16x32_bf16(
                        af[mi], bu[ni], accU[mi][ni], 0, 0, 0);
                }
        }

        __syncthreads();
    }

    // ---- epilogue: SwiGLU, write h as bf16 ----
#pragma unroll
    for (int ni = 0; ni < 2; ++ni) {
        int col = n0 + wn + ni * 16 + (lane & 15);
        float gb = gbias[col], ub = ubias[col];
#pragma unroll
        for (int mi = 0; mi < 4; ++mi) {
#pragma unroll
            for (int j = 0; j < 4; ++j) {
                int row = m0 + wm + mi * 16 + ((lane >> 4) * 4) + j;
                float g = accG[mi][ni][j] + gb;
                float u = accU[mi][ni][j] + ub;
                float sig = 1.f / (1.f + __expf(-g));
                float hv = g * sig * u;
                h[(size_t)row * INTER + col] = f2bf(hv);
            }
        }
    }
}

// ---------------------------------------------------------------------------
// Kernel 3: down GEMM: y = h @ Wd^T + bias (fp32 out)
// Block: 256 thr. Tile: 128(M) x 64(N), BK=64, K=INTER (172 tiles).
// Grid: 1024 blocks, 1D, M-siblings adjacent.
// ---------------------------------------------------------------------------
__global__ __launch_bounds__(256) void k_down(
    const unsigned short* __restrict__ h,    // [SEQ][INTER] bf16
    const int* __restrict__ dqw, const int* __restrict__ dqz,
    const float* __restrict__ dsc, const float* __restrict__ dbias,
    float* __restrict__ y)                   // [SEQ][HIDDEN] fp32
{
    __shared__ __align__(16) unsigned short At[128 * 64]; // 16 KB
    __shared__ __align__(16) unsigned short Bd[64 * 64];  // 8 KB

    const int bid = blockIdx.x;
    const int mt  = bid & 15;
    const int nt  = bid >> 4;
    const int m0  = mt * 128;
    const int n0  = nt * 64;

    const int t    = threadIdx.x;
    const int lane = t & 63;
    const int wave = t >> 6;

    const int wm = (wave >> 1) * 64;
    const int wn = (wave & 1) * 32;

    f32x4 acc[4][2];
#pragma unroll
    for (int mi = 0; mi < 4; ++mi)
#pragma unroll
        for (int ni = 0; ni < 2; ++ni)
            acc[mi][ni] = (f32x4){0.f, 0.f, 0.f, 0.f};

    for (int kt = 0; kt < INTER / 64; ++kt) {
        const int k0  = kt * 64;
        const int grp = k0 >> 7;

        // ---- stage A (h tile) ----
#pragma unroll
        for (int c = 0; c < 4; ++c) {
            int idx  = t + 256 * c;
            int row  = idx >> 3;
            int colb = (idx & 7) * 16;
            int scol = colb ^ ((row & 7) << 4);
            const char* g = (const char*)(h + (size_t)(m0 + row) * INTER + k0) + scol;
            gload_lds16(g, (char*)At + idx * 16);
        }

        // ---- stage B (down weights, dequant) ----
#pragma unroll
        for (int c = 0; c < 4; ++c) {
            int row  = (t >> 4) + 16 * c;
            int col4 = (t & 15) * 4;
            int gi   = n0 + row;
            int4  q = *(const int4*)(dqw + (size_t)gi * INTER + k0 + col4);
            int   z = dqz[gi * (INTER / 128) + grp];
            float s = dsc[gi * (INTER / 128) + grp];
            float zs = -(float)z * s;
            ushort4 w;
            w.x = f2bf(fmaf((float)q.x, s, zs));
            w.y = f2bf(fmaf((float)q.y, s, zs));
            w.z = f2bf(fmaf((float)q.z, s, zs));
            w.w = f2bf(fmaf((float)q.w, s, zs));
            *(ushort4*)((char*)Bd + (row * 128 + ((col4 * 2) ^ ((row & 7) << 4)))) = w;
        }

        __syncthreads();

#pragma unroll
        for (int kk = 0; kk < 2; ++kk) {
            bf16x8 af[4], bd[2];
#pragma unroll
            for (int mi = 0; mi < 4; ++mi) {
                int row  = wm + mi * 16 + (lane & 15);
                int colb = kk * 64 + ((lane >> 4) * 16);
                af[mi] = *(const bf16x8*)((const char*)At + row * 128 +
                                          (colb ^ ((row & 7) << 4)));
            }
#pragma unroll
            for (int ni = 0; ni < 2; ++ni) {
                int row  = wn + ni * 16 + (lane & 15);
                int colb = kk * 64 + ((lane >> 4) * 16);
                bd[ni] = *(const bf16x8*)((const char*)Bd + row * 128 +
                                          (colb ^ ((row & 7) << 4)));
            }
#pragma unroll
            for (int mi = 0; mi < 4; ++mi)
#pragma unroll
                for (int ni = 0; ni < 2; ++ni)
                    acc[mi][ni] = __builtin_amdgcn_mfma_f32_16x16x32_bf16(
                        af[mi], bd[ni], acc[mi][ni], 0, 0, 0);
        }

        __syncthreads();
    }

    // ---- epilogue: bias + fp32 store ----
#pragma unroll
    for (int ni = 0; ni < 2; ++ni) {
        int col = n0 + wn + ni * 16 + (lane & 15);
        float db = dbias[col];
#pragma unroll
        for (int mi = 0; mi < 4; ++mi) {
#pragma unroll
            for (int j = 0; j < 4; ++j) {
                int row = m0 + wm + mi * 16 + ((lane >> 4) * 4) + j;
                y[(size_t)row * HIDDEN + col] = acc[mi][ni][j] + db;
            }
        }
    }
}

// ---------------------------------------------------------------------------
extern "C" void kernel_launch(void* const* d_in, const int* in_sizes, int n_in,
                              void* d_out, int out_size, void* d_ws, size_t ws_size,
                              hipStream_t stream) {
    const float* x    = (const float*)d_in[0];
    const int*   gqw  = (const int*)d_in[1];
    const int*   gqz  = (const int*)d_in[2];
    const float* gsc  = (const float*)d_in[3];
    const float* gbia = (const float*)d_in[4];
    const int*   uqw  = (const int*)d_in[5];
    const int*   uqz  = (const int*)d_in[6];
    const float* usc  = (const float*)d_in[7];
    const float* ubia = (const float*)d_in[8];
    const int*   dqw  = (const int*)d_in[9];
    const int*   dqz  = (const int*)d_in[10];
    const float* dsc  = (const float*)d_in[11];
    const float* dbia = (const float*)d_in[12];
    float* y = (float*)d_out;

    unsigned short* xb = (unsigned short*)d_ws;                    // 16.8 MB
    unsigned short* hh = xb + (size_t)SEQ * HIDDEN;                // 45.1 MB

    k_cvt_x<<<(SEQ * HIDDEN) / 1024, 256, 0, stream>>>(x, xb);
    k_gate_up<<<dim3(172 * 16), 256, 0, stream>>>(
        xb, gqw, gqz, gsc, gbia, uqw, uqz, usc, ubia, hh);
    k_down<<<dim3(64 * 16), 256, 0, stream>>>(
        hh, dqw, dqz, dsc, dbia, y);
}

// Round 4
// 714.811 us; speedup vs baseline: 2.3802x; 1.8595x over previous
//
#include <hip/hip_runtime.h>
#include <hip/hip_bf16.h>
#include <stdint.h>

#define SEQ    2048
#define HIDDEN 4096
#define INTER  11008

typedef short bf16x8 __attribute__((ext_vector_type(8)));
typedef float f32x4  __attribute__((ext_vector_type(4)));
typedef unsigned short u16x8 __attribute__((ext_vector_type(8)));

__device__ __forceinline__ unsigned short f2bf(float f) {
    union { __hip_bfloat16 h; unsigned short u; } v;
    v.h = __float2bfloat16(f);
    return v.u;
}

__device__ __forceinline__ void gload_lds16(const void* g, void* lds) {
    __builtin_amdgcn_global_load_lds(
        (const __attribute__((address_space(1))) uint32_t*)g,
        (__attribute__((address_space(3))) uint32_t*)lds,
        16, 0, 0);
}

// ---------------------------------------------------------------------------
// x fp32 -> bf16
// ---------------------------------------------------------------------------
__global__ __launch_bounds__(256) void k_cvt_x(const float* __restrict__ x,
                                               unsigned short* __restrict__ xb) {
    int i = (blockIdx.x * 256 + threadIdx.x) * 4;
    float4 v = *(const float4*)(x + i);
    ushort4 o;
    o.x = f2bf(v.x); o.y = f2bf(v.y); o.z = f2bf(v.z); o.w = f2bf(v.w);
    *(ushort4*)(xb + i) = o;
}

// ---------------------------------------------------------------------------
// Weight dequant: int32 codes -> bf16. 8 codes/thread.
// group index = i>>7 exactly (128 | I for both I=4096 and I=11008).
// ---------------------------------------------------------------------------
__global__ __launch_bounds__(256) void k_dequant(
    const int* __restrict__ qw, const int* __restrict__ qz,
    const float* __restrict__ sc, unsigned short* __restrict__ w)
{
    size_t i = ((size_t)blockIdx.x * 256 + threadIdx.x) * 8;
    int gi = (int)(i >> 7);
    int   z = qz[gi];
    float s = sc[gi];
    float zs = -(float)z * s;
    int4 q0 = *(const int4*)(qw + i);
    int4 q1 = *(const int4*)(qw + i + 4);
    u16x8 o;
    o[0] = f2bf(fmaf((float)q0.x, s, zs));
    o[1] = f2bf(fmaf((float)q0.y, s, zs));
    o[2] = f2bf(fmaf((float)q0.z, s, zs));
    o[3] = f2bf(fmaf((float)q0.w, s, zs));
    o[4] = f2bf(fmaf((float)q1.x, s, zs));
    o[5] = f2bf(fmaf((float)q1.y, s, zs));
    o[6] = f2bf(fmaf((float)q1.z, s, zs));
    o[7] = f2bf(fmaf((float)q1.w, s, zs));
    *(u16x8*)(w + i) = o;
}

// ===========================================================================
// FAST PATH: pure bf16 GEMMs, all operands staged via global_load_lds.
// ===========================================================================

// Fused gate+up GEMM + SwiGLU -> h (bf16).
// 512 thr (8 waves: 2M x 4N). Tile 128(M) x 128(N), BK=64. Wave 64x32 dual.
// Grid 1376, bid: mt = bid & 15 (M-siblings adjacent for weight-line reuse).
__global__ __launch_bounds__(512) void k_gate_up(
    const unsigned short* __restrict__ xb,   // [SEQ][HIDDEN] bf16
    const unsigned short* __restrict__ wg,   // [INTER][HIDDEN] bf16
    const unsigned short* __restrict__ wu,   // [INTER][HIDDEN] bf16
    const float* __restrict__ gbias, const float* __restrict__ ubias,
    unsigned short* __restrict__ h)          // [SEQ][INTER] bf16
{
    __shared__ __align__(16) unsigned short At[128 * 64]; // 16 KB, swizzled
    __shared__ __align__(16) unsigned short Bg[128 * 64]; // 16 KB, swizzled
    __shared__ __align__(16) unsigned short Bu[128 * 64]; // 16 KB, swizzled

    const int bid = blockIdx.x;
    const int mt  = bid & 15;
    const int nt  = bid >> 4;
    const int m0  = mt * 128;
    const int n0  = nt * 128;

    const int t    = threadIdx.x;
    const int lane = t & 63;
    const int wave = t >> 6;
    const int wm = (wave >> 2) * 64;
    const int wn = (wave & 3) * 32;

    f32x4 accG[4][2], accU[4][2];
#pragma unroll
    for (int mi = 0; mi < 4; ++mi)
#pragma unroll
        for (int ni = 0; ni < 2; ++ni) {
            accG[mi][ni] = (f32x4){0.f, 0.f, 0.f, 0.f};
            accU[mi][ni] = (f32x4){0.f, 0.f, 0.f, 0.f};
        }

    for (int kt = 0; kt < HIDDEN / 64; ++kt) {
        const int k0 = kt * 64;

        // chunk geometry shared by all three tiles: 1024 x 16B chunks,
        // row = idx>>3, swizzled col = ((idx&7)*16) ^ ((row&7)<<4)
#pragma unroll
        for (int cc = 0; cc < 2; ++cc) {
            int idx  = t + 512 * cc;
            int row  = idx >> 3;
            int scol = ((idx & 7) * 16) ^ ((row & 7) << 4);
            gload_lds16((const char*)(xb + (size_t)(m0 + row) * HIDDEN + k0) + scol,
                        (char*)At + idx * 16);
        }
#pragma unroll
        for (int cc = 0; cc < 2; ++cc) {
            int idx  = t + 512 * cc;
            int row  = idx >> 3;
            int scol = ((idx & 7) * 16) ^ ((row & 7) << 4);
            gload_lds16((const char*)(wg + (size_t)(n0 + row) * HIDDEN + k0) + scol,
                        (char*)Bg + idx * 16);
        }
#pragma unroll
        for (int cc = 0; cc < 2; ++cc) {
            int idx  = t + 512 * cc;
            int row  = idx >> 3;
            int scol = ((idx & 7) * 16) ^ ((row & 7) << 4);
            gload_lds16((const char*)(wu + (size_t)(n0 + row) * HIDDEN + k0) + scol,
                        (char*)Bu + idx * 16);
        }

        __syncthreads();

#pragma unroll
        for (int kk = 0; kk < 2; ++kk) {
            bf16x8 af[4], bg[2], bu[2];
#pragma unroll
            for (int mi = 0; mi < 4; ++mi) {
                int row  = wm + mi * 16 + (lane & 15);
                int colb = kk * 64 + ((lane >> 4) * 16);
                af[mi] = *(const bf16x8*)((const char*)At + row * 128 +
                                          (colb ^ ((row & 7) << 4)));
            }
#pragma unroll
            for (int ni = 0; ni < 2; ++ni) {
                int row  = wn + ni * 16 + (lane & 15);
                int colb = kk * 64 + ((lane >> 4) * 16);
                int off  = row * 128 + (colb ^ ((row & 7) << 4));
                bg[ni] = *(const bf16x8*)((const char*)Bg + off);
                bu[ni] = *(const bf16x8*)((const char*)Bu + off);
            }
#pragma unroll
            for (int mi = 0; mi < 4; ++mi)
#pragma unroll
                for (int ni = 0; ni < 2; ++ni) {
                    accG[mi][ni] = __builtin_amdgcn_mfma_f32_16x16x32_bf16(
                        af[mi], bg[ni], accG[mi][ni], 0, 0, 0);
                    accU[mi][ni] = __builtin_amdgcn_mfma_f32_16x16x32_bf16(
                        af[mi], bu[ni], accU[mi][ni], 0, 0, 0);
                }
        }

        __syncthreads();
    }

#pragma unroll
    for (int ni = 0; ni < 2; ++ni) {
        int col = n0 + wn + ni * 16 + (lane & 15);
        float gb = gbias[col], ub = ubias[col];
#pragma unroll
        for (int mi = 0; mi < 4; ++mi) {
#pragma unroll
            for (int j = 0; j < 4; ++j) {
                int row = m0 + wm + mi * 16 + ((lane >> 4) * 4) + j;
                float g = accG[mi][ni][j] + gb;
                float u = accU[mi][ni][j] + ub;
                float sig = 1.f / (1.f + __expf(-g));
                h[(size_t)row * INTER + col] = f2bf(g * sig * u);
            }
        }
    }
}

// Down GEMM: y = h @ Wd^T + bias (fp32 out). 512 thr, tile 128x128, BK=64.
__global__ __launch_bounds__(512) void k_down(
    const unsigned short* __restrict__ h,    // [SEQ][INTER] bf16
    const unsigned short* __restrict__ wd,   // [HIDDEN][INTER] bf16
    const float* __restrict__ dbias,
    float* __restrict__ y)                   // [SEQ][HIDDEN] fp32
{
    __shared__ __align__(16) unsigned short At[128 * 64]; // 16 KB
    __shared__ __align__(16) unsigned short Bd[128 * 64]; // 16 KB

    const int bid = blockIdx.x;
    const int mt  = bid & 15;
    const int nt  = bid >> 4;
    const int m0  = mt * 128;
    const int n0  = nt * 128;

    const int t    = threadIdx.x;
    const int lane = t & 63;
    const int wave = t >> 6;
    const int wm = (wave >> 2) * 64;
    const int wn = (wave & 3) * 32;

    f32x4 acc[4][2];
#pragma unroll
    for (int mi = 0; mi < 4; ++mi)
#pragma unroll
        for (int ni = 0; ni < 2; ++ni)
            acc[mi][ni] = (f32x4){0.f, 0.f, 0.f, 0.f};

    for (int kt = 0; kt < INTER / 64; ++kt) {
        const int k0 = kt * 64;

#pragma unroll
        for (int cc = 0; cc < 2; ++cc) {
            int idx  = t + 512 * cc;
            int row  = idx >> 3;
            int scol = ((idx & 7) * 16) ^ ((row & 7) << 4);
            gload_lds16((const char*)(h + (size_t)(m0 + row) * INTER + k0) + scol,
                        (char*)At + idx * 16);
        }
#pragma unroll
        for (int cc = 0; cc < 2; ++cc) {
            int idx  = t + 512 * cc;
            int row  = idx >> 3;
            int scol = ((idx & 7) * 16) ^ ((row & 7) << 4);
            gload_lds16((const char*)(wd + (size_t)(n0 + row) * INTER + k0) + scol,
                        (char*)Bd + idx * 16);
        }

        __syncthreads();

#pragma unroll
        for (int kk = 0; kk < 2; ++kk) {
            bf16x8 af[4], bd[2];
#pragma unroll
            for (int mi = 0; mi < 4; ++mi) {
                int row  = wm + mi * 16 + (lane & 15);
                int colb = kk * 64 + ((lane >> 4) * 16);
                af[mi] = *(const bf16x8*)((const char*)At + row * 128 +
                                          (colb ^ ((row & 7) << 4)));
            }
#pragma unroll
            for (int ni = 0; ni < 2; ++ni) {
                int row  = wn + ni * 16 + (lane & 15);
                int colb = kk * 64 + ((lane >> 4) * 16);
                bd[ni] = *(const bf16x8*)((const char*)Bd + row * 128 +
                                          (colb ^ ((row & 7) << 4)));
            }
#pragma unroll
            for (int mi = 0; mi < 4; ++mi)
#pragma unroll
                for (int ni = 0; ni < 2; ++ni)
                    acc[mi][ni] = __builtin_amdgcn_mfma_f32_16x16x32_bf16(
                        af[mi], bd[ni], acc[mi][ni], 0, 0, 0);
        }

        __syncthreads();
    }

#pragma unroll
    for (int ni = 0; ni < 2; ++ni) {
        int col = n0 + wn + ni * 16 + (lane & 15);
        float db = dbias[col];
#pragma unroll
        for (int mi = 0; mi < 4; ++mi) {
#pragma unroll
            for (int j = 0; j < 4; ++j) {
                int row = m0 + wm + mi * 16 + ((lane >> 4) * 4) + j;
                y[(size_t)row * HIDDEN + col] = acc[mi][ni][j] + db;
            }
        }
    }
}

// ===========================================================================
// FALLBACK PATH (round-3 fused-dequant kernels) — used if ws too small.
// ===========================================================================
__global__ __launch_bounds__(256) void k_gate_up_q(
    const unsigned short* __restrict__ xb,
    const int* __restrict__ gqw, const int* __restrict__ gqz,
    const float* __restrict__ gsc, const float* __restrict__ gbias,
    const int* __restrict__ uqw, const int* __restrict__ uqz,
    const float* __restrict__ usc, const float* __restrict__ ubias,
    unsigned short* __restrict__ h)
{
    __shared__ __align__(16) unsigned short At[128 * 64];
    __shared__ __align__(16) unsigned short Bg[64 * 64];
    __shared__ __align__(16) unsigned short Bu[64 * 64];

    const int bid = blockIdx.x;
    const int mt  = bid & 15;
    const int nt  = bid >> 4;
    const int m0  = mt * 128;
    const int n0  = nt * 64;

    const int t    = threadIdx.x;
    const int lane = t & 63;
    const int wave = t >> 6;
    const int wm = (wave >> 1) * 64;
    const int wn = (wave & 1) * 32;

    f32x4 accG[4][2], accU[4][2];
#pragma unroll
    for (int mi = 0; mi < 4; ++mi)
#pragma unroll
        for (int ni = 0; ni < 2; ++ni) {
            accG[mi][ni] = (f32x4){0.f, 0.f, 0.f, 0.f};
            accU[mi][ni] = (f32x4){0.f, 0.f, 0.f, 0.f};
        }

    for (int kt = 0; kt < HIDDEN / 64; ++kt) {
        const int k0  = kt * 64;
        const int grp = k0 >> 7;
#pragma unroll
        for (int c = 0; c < 4; ++c) {
            int idx  = t + 256 * c;
            int row  = idx >> 3;
            int scol = ((idx & 7) * 16) ^ ((row & 7) << 4);
            gload_lds16((const char*)(xb + (size_t)(m0 + row) * HIDDEN + k0) + scol,
                        (char*)At + idx * 16);
        }
#pragma unroll
        for (int c = 0; c < 4; ++c) {
            int row  = (t >> 4) + 16 * c;
            int col4 = (t & 15) * 4;
            int gi   = n0 + row;
            int lbyte = row * 128 + ((col4 * 2) ^ ((row & 7) << 4));
            {
                int4  q = *(const int4*)(gqw + (size_t)gi * HIDDEN + k0 + col4);
                int   z = gqz[gi * (HIDDEN / 128) + grp];
                float s = gsc[gi * (HIDDEN / 128) + grp];
                float zs = -(float)z * s;
                ushort4 w;
                w.x = f2bf(fmaf((float)q.x, s, zs));
                w.y = f2bf(fmaf((float)q.y, s, zs));
                w.z = f2bf(fmaf((float)q.z, s, zs));
                w.w = f2bf(fmaf((float)q.w, s, zs));
                *(ushort4*)((char*)Bg + lbyte) = w;
            }
            {
                int4  q = *(const int4*)(uqw + (size_t)gi * HIDDEN + k0 + col4);
                int   z = uqz[gi * (HIDDEN / 128) + grp];
                float s = usc[gi * (HIDDEN / 128) + grp];
                float zs = -(float)z * s;
                ushort4 w;
                w.x = f2bf(fmaf((float)q.x, s, zs));
                w.y = f2bf(fmaf((float)q.y, s, zs));
                w.z = f2bf(fmaf((float)q.z, s, zs));
                w.w = f2bf(fmaf((float)q.w, s, zs));
                *(ushort4*)((char*)Bu + lbyte) = w;
            }
        }
        __syncthreads();
#pragma unroll
        for (int kk = 0; kk < 2; ++kk) {
            bf16x8 af[4], bg[2], bu[2];
#pragma unroll
            for (int mi = 0; mi < 4; ++mi) {
                int row  = wm + mi * 16 + (lane & 15);
                int colb = kk * 64 + ((lane >> 4) * 16);
                af[mi] = *(const bf16x8*)((const char*)At + row * 128 +
                                          (colb ^ ((row & 7) << 4)));
            }
#pragma unroll
            for (int ni = 0; ni < 2; ++ni) {
                int row  = wn + ni * 16 + (lane & 15);
                int colb = kk * 64 + ((lane >> 4) * 16);
                int off  = row * 128 + (colb ^ ((row & 7) << 4));
                bg[ni] = *(const bf16x8*)((const char*)Bg + off);
                bu[ni] = *(const bf16x8*)((const char*)Bu + off);
            }
#pragma unroll
            for (int mi = 0; mi < 4; ++mi)
#pragma unroll
                for (int ni = 0; ni < 2; ++ni) {
                    accG[mi][ni] = __builtin_amdgcn_mfma_f32_16x16x32_bf16(
                        af[mi], bg[ni], accG[mi][ni], 0, 0, 0);
                    accU[mi][ni] = __builtin_amdgcn_mfma_f32_16x16x32_bf16(
                        af[mi], bu[ni], accU[mi][ni], 0, 0, 0);
                }
        }
        __syncthreads();
    }
#pragma unroll
    for (int ni = 0; ni < 2; ++ni) {
        int col = n0 + wn + ni * 16 + (lane & 15);
        float gb = gbias[col], ub = ubias[col];
#pragma unroll
        for (int mi = 0; mi < 4; ++mi) {
#pragma unroll
            for (int j = 0; j < 4; ++j) {
                int row = m0 + wm + mi * 16 + ((lane >> 4) * 4) + j;
                float g = accG[mi][ni][j] + gb;
                float u = accU[mi][ni][j] + ub;
                float sig = 1.f / (1.f + __expf(-g));
                h[(size_t)row * INTER + col] = f2bf(g * sig * u);
            }
        }
    }
}

__global__ __launch_bounds__(256) void k_down_q(
    const unsigned short* __restrict__ h,
    const int* __restrict__ dqw, const int* __restrict__ dqz,
    const float* __restrict__ dsc, const float* __restrict__ dbias,
    float* __restrict__ y)
{
    __shared__ __align__(16) unsigned short At[128 * 64];
    __shared__ __align__(16) unsigned short Bd[64 * 64];

    const int bid = blockIdx.x;
    const int mt  = bid & 15;
    const int nt  = bid >> 4;
    const int m0  = mt * 128;
    const int n0  = nt * 64;

    const int t    = threadIdx.x;
    const int lane = t & 63;
    const int wave = t >> 6;
    const int wm = (wave >> 1) * 64;
    const int wn = (wave & 1) * 32;

    f32x4 acc[4][2];
#pragma unroll
    for (int mi = 0; mi < 4; ++mi)
#pragma unroll
        for (int ni = 0; ni < 2; ++ni)
            acc[mi][ni] = (f32x4){0.f, 0.f, 0.f, 0.f};

    for (int kt = 0; kt < INTER / 64; ++kt) {
        const int k0  = kt * 64;
        const int grp = k0 >> 7;
#pragma unroll
        for (int c = 0; c < 4; ++c) {
            int idx  = t + 256 * c;
            int row  = idx >> 3;
            int scol = ((idx & 7) * 16) ^ ((row & 7) << 4);
            gload_lds16((const char*)(h + (size_t)(m0 + row) * INTER + k0) + scol,
                        (char*)At + idx * 16);
        }
#pragma unroll
        for (int c = 0; c < 4; ++c) {
            int row  = (t >> 4) + 16 * c;
            int col4 = (t & 15) * 4;
            int gi   = n0 + row;
            int4  q = *(const int4*)(dqw + (size_t)gi * INTER + k0 + col4);
            int   z = dqz[gi * (INTER / 128) + grp];
            float s = dsc[gi * (INTER / 128) + grp];
            float zs = -(float)z * s;
            ushort4 w;
            w.x = f2bf(fmaf((float)q.x, s, zs));
            w.y = f2bf(fmaf((float)q.y, s, zs));
            w.z = f2bf(fmaf((float)q.z, s, zs));
            w.w = f2bf(fmaf((float)q.w, s, zs));
            *(ushort4*)((char*)Bd + (row * 128 + ((col4 * 2) ^ ((row & 7) << 4)))) = w;
        }
        __syncthreads();
#pragma unroll
        for (int kk = 0; kk < 2; ++kk) {
            bf16x8 af[4], bd[2];
#pragma unroll
            for (int mi = 0; mi < 4; ++mi) {
                int row  = wm + mi * 16 + (lane & 15);
                int colb = kk * 64 + ((lane >> 4) * 16);
                af[mi] = *(const bf16x8*)((const char*)At + row * 128 +
                                          (colb ^ ((row & 7) << 4)));
            }
#pragma unroll
            for (int ni = 0; ni < 2; ++ni) {
                int row  = wn + ni * 16 + (lane & 15);
                int colb = kk * 64 + ((lane >> 4) * 16);
                bd[ni] = *(const bf16x8*)((const char*)Bd + row * 128 +
                                          (colb ^ ((row & 7) << 4)));
            }
#pragma unroll
            for (int mi = 0; mi < 4; ++mi)
#pragma unroll
                for (int ni = 0; ni < 2; ++ni)
                    acc[mi][ni] = __builtin_amdgcn_mfma_f32_16x16x32_bf16(
                        af[mi], bd[ni], acc[mi][ni], 0, 0, 0);
        }
        __syncthreads();
    }
#pragma unroll
    for (int ni = 0; ni < 2; ++ni) {
        int col = n0 + wn + ni * 16 + (lane & 15);
        float db = dbias[col];
#pragma unroll
        for (int mi = 0; mi < 4; ++mi) {
#pragma unroll
            for (int j = 0; j < 4; ++j) {
                int row = m0 + wm + mi * 16 + ((lane >> 4) * 4) + j;
                y[(size_t)row * HIDDEN + col] = acc[mi][ni][j] + db;
            }
        }
    }
}

// ---------------------------------------------------------------------------
extern "C" void kernel_launch(void* const* d_in, const int* in_sizes, int n_in,
                              void* d_out, int out_size, void* d_ws, size_t ws_size,
                              hipStream_t stream) {
    const float* x    = (const float*)d_in[0];
    const int*   gqw  = (const int*)d_in[1];
    const int*   gqz  = (const int*)d_in[2];
    const float* gsc  = (const float*)d_in[3];
    const float* gbia = (const float*)d_in[4];
    const int*   uqw  = (const int*)d_in[5];
    const int*   uqz  = (const int*)d_in[6];
    const float* usc  = (const float*)d_in[7];
    const float* ubia = (const float*)d_in[8];
    const int*   dqw  = (const int*)d_in[9];
    const int*   dqz  = (const int*)d_in[10];
    const float* dsc  = (const float*)d_in[11];
    const float* dbia = (const float*)d_in[12];
    float* y = (float*)d_out;

    const size_t N_XB = (size_t)SEQ * HIDDEN;      // 8.4M elems
    const size_t N_H  = (size_t)SEQ * INTER;       // 22.5M elems
    const size_t N_W  = (size_t)INTER * HIDDEN;    // 45.1M elems (all three)

    unsigned short* xb = (unsigned short*)d_ws;
    unsigned short* hh = xb + N_XB;

    const size_t need = (N_XB + N_H + 2 * N_W) * sizeof(unsigned short);

    k_cvt_x<<<(SEQ * HIDDEN) / 1024, 256, 0, stream>>>(x, xb);

    if (ws_size >= need) {
        unsigned short* wgb = hh + N_H;
        unsigned short* wub = wgb + N_W;
        unsigned short* wdb = wgb;                 // reused after k_gate_up

        const int dq_blocks = (int)(N_W / 2048);   // 22016
        k_dequant<<<dq_blocks, 256, 0, stream>>>(gqw, gqz, gsc, wgb);
        k_dequant<<<dq_blocks, 256, 0, stream>>>(uqw, uqz, usc, wub);
        k_gate_up<<<dim3((INTER / 128) * 16), 512, 0, stream>>>(
            xb, wgb, wub, gbia, ubia, hh);
        k_dequant<<<dq_blocks, 256, 0, stream>>>(dqw, dqz, dsc, wdb);
        k_down<<<dim3((HIDDEN / 128) * 16), 512, 0, stream>>>(hh, wdb, dbia, y);
    } else {
        k_gate_up_q<<<dim3((INTER / 64) * 16), 256, 0, stream>>>(
            xb, gqw, gqz, gsc, gbia, uqw, uqz, usc, ubia, hh);
        k_down_q<<<dim3((HIDDEN / 64) * 16), 256, 0, stream>>>(
            hh, dqw, dqz, dsc, dbia, y);
    }
}